// Round 4
// baseline (1147.494 us; speedup 1.0000x reference)
//
#include <hip/hip_runtime.h>
#include <stdint.h>

// ParallelFcWithAttention: B=16384, F=10, D=512, H=8, DH=64
// v5: barrier-free phase-1 main loop. B (wqkv) fragments loaded straight from
// global (L1/L2-hot) into registers with 1-slab prefetch; sA (P) is read-only
// LDS; only 2 barriers per head (attention epilogue). Phase 2 unchanged (v4
// BK=32 dbuf + counted vmcnt), scratch relocated.

typedef __bf16 bf16;
typedef __bf16 bf16x8 __attribute__((ext_vector_type(8)));
typedef float f32x4 __attribute__((ext_vector_type(4)));

#define EPS 1e-5f

static constexpr size_t O_ELEMS   = (size_t)16384 * 10 * 512;   // 83,886,080
static constexpr size_t O_BYTES   = O_ELEMS * 2;                // 167,772,160
static constexpr size_t WQKV_BYTES = (size_t)8 * 192 * 512 * 2; // 1,572,864

__device__ __forceinline__ void async_copy16(void* lds, const void* g) {
  // wave-uniform LDS base; HW scatters lane i at base + i*16; global addr per-lane
  __builtin_amdgcn_global_load_lds(
      (const __attribute__((address_space(1))) uint32_t*)g,
      (__attribute__((address_space(3))) uint32_t*)lds, 16, 0, 0);
}

// ---------------- pack weights to bf16 ----------------
// wqkv layout: [h][0:64 = Wq rows h*64.., 64:128 = Wk, 128:192 = Wv][512]
__global__ __launch_bounds__(256) void pack_weights(
    const float* __restrict__ Wq, const float* __restrict__ Wk,
    const float* __restrict__ Wv, const float* __restrict__ Wo,
    bf16* __restrict__ wqkv, bf16* __restrict__ wob) {
  int idx = blockIdx.x * 256 + threadIdx.x;
#pragma unroll
  for (int u = 0; u < 4; ++u) {
    int i = idx + u * 262144;
    if (i < 786432) {
      int pr = i >> 9, k = i & 511;
      int h = pr / 192, w = pr - h * 192;
      int t = w >> 6, r = w & 63;
      const float* src = (t == 0) ? Wq : ((t == 1) ? Wk : Wv);
      wqkv[i] = (bf16)src[(h * 64 + r) * 512 + k];
    } else {
      int j = i - 786432;
      wob[j] = (bf16)Wo[j];
    }
  }
}

// ---------------- fused kernel ----------------
// 512 threads, 8 batch elems (80 rows) per block. 1 block/CU.
// LDS (118528 B total):
//   phase 1: sA  @0      [8 slabs][80 rows][128B] XOR-swizzled   81920
//            sQK @81920  [88][256] q|k spill, swizzled           22528
//            vbuf@104448 [80][64] bf16 v values                  10240
//            scp @114688 [8][10][12] f32 attn weights             3840
//   phase 2 overlay: Ab0@0 Ab1@5120 (5120 each) | Bb0@10240 Bb1@43008 (32768 each)
//            lnb @0 [80][520] bf16 | partial @83200 [80][4][2] | stats @85760 [80][2]
__global__ __launch_bounds__(512, 2) void kern_fused(
    const float* __restrict__ x, const float* __restrict__ Wf,
    const float* __restrict__ bfv, const bf16* __restrict__ wqkv,
    const float* __restrict__ bq, const float* __restrict__ bk,
    const float* __restrict__ bv, bf16* __restrict__ O,
    const bf16* __restrict__ wob, const float* __restrict__ bo,
    const float* __restrict__ gamma, const float* __restrict__ beta,
    float* __restrict__ out) {
  __shared__ __align__(16) char smem[118528];
  char* sA  = smem;
  char* sQK = smem + 81920;
  bf16* vbuf = (bf16*)(smem + 104448);
  float* scp = (float*)(smem + 114688);

  const int tid = threadIdx.x;
  const int wave = tid >> 6;
  const int lane = tid & 63;
  const int lm = lane & 15;
  const int lg = lane >> 4;
  const int wm = wave >> 2;
  const int wn = wave & 3;
  const int b0 = blockIdx.x * 8;
  const int lr = lane >> 3;
  const int kcg = (lane & 7) ^ lr;         // pre-swizzled k-chunk (phase-2 staging)
  const int x7 = lm & 7;

  // ---- compute P = relu(x*Wf + bf) into sA (80 real rows) ----
#pragma unroll
  for (int it = 0; it < 10; ++it) {
    int c = tid + it * 512;                // 5120 chunks: c = s*640 + r*8 + kcp
    int s = c / 640, rem = c - s * 640;
    int r = rem >> 3, kcp = rem & 7;
    int kc = kcp ^ (r & 7);
    int k = s * 64 + kc * 8;
    int bl = r / 10, f = r - bl * 10;
    float xv = x[(b0 + bl) * 10 + f];
    const float* wf = Wf + f * 512 + k;
    const float* bp = bfv + f * 512 + k;
    bf16x8 pv;
#pragma unroll
    for (int j = 0; j < 8; ++j) pv[j] = (bf16)fmaxf(xv * wf[j] + bp[j], 0.f);
    *(bf16x8*)(sA + s * 10240 + r * 128 + kcp * 16) = pv;
  }
  __syncthreads();   // P visible; sA is read-only from here on

  // ---- per-lane base for B-fragment global loads ----
  // B-frag for (t=h*8+s, nt, kk): lane reads wqkv[h][wn*48+nt*16+lm][s*64+kk*32+lg*8 ..+7]
  const bf16* wBlane = wqkv + (size_t)(wn * 48 + lm) * 512 + lg * 8;

  bf16x8 b0f[3][2], b1f[3][2];
#pragma unroll
  for (int nt = 0; nt < 3; ++nt)
#pragma unroll
    for (int kk = 0; kk < 2; ++kk)
      b0f[nt][kk] = *(const bf16x8*)(wBlane + nt * 8192 + kk * 32);   // t=0

  for (int h = 0; h < 8; ++h) {
    f32x4 acc[3][3];
#pragma unroll
    for (int i = 0; i < 3; ++i)
#pragma unroll
      for (int j = 0; j < 3; ++j) { f32x4 z = {0.f, 0.f, 0.f, 0.f}; acc[i][j] = z; }

    // ---- barrier-free GEMM over K=512 (8 slabs), B prefetched 1 slab ahead ----
#pragma unroll
    for (int s = 0; s < 8; ++s) {
      const int t = h * 8 + s;
      bf16x8 (*bc)[2] = (s & 1) ? b1f : b0f;
      bf16x8 (*bn)[2] = (s & 1) ? b0f : b1f;
      if (t < 63) {
        const int tn = t + 1;
        const bf16* p = wBlane + (size_t)(tn >> 3) * 98304 + (tn & 7) * 64;
#pragma unroll
        for (int nt = 0; nt < 3; ++nt)
#pragma unroll
          for (int kk = 0; kk < 2; ++kk)
            bn[nt][kk] = *(const bf16x8*)(p + nt * 8192 + kk * 32);
      }
#pragma unroll
      for (int kk = 0; kk < 2; ++kk) {
        int ch = ((kk * 4 + lg) ^ x7) << 4;   // m&7 == lm&7
        bf16x8 af[3];
#pragma unroll
        for (int mt = 0; mt < 3; ++mt)
          if (mt < 2 || wm == 0)
            af[mt] = *(const bf16x8*)(sA + s * 10240 + (wm * 48 + mt * 16 + lm) * 128 + ch);
        __builtin_amdgcn_s_setprio(1);
#pragma unroll
        for (int mt = 0; mt < 3; ++mt)
          if (mt < 2 || wm == 0)
#pragma unroll
            for (int nt = 0; nt < 3; ++nt)
              acc[mt][nt] = __builtin_amdgcn_mfma_f32_16x16x32_bf16(af[mt], bc[nt][kk], acc[mt][nt], 0, 0, 0);
        __builtin_amdgcn_s_setprio(0);
      }
    }

    __syncthreads();  // barrier A: prev head's sQK/vbuf/scp readers are done

    // ---- spill q,k (+bias) -> sQK (swizzled), v (+bias) -> vbuf ----
    {
      float bias[3];
#pragma unroll
      for (int nt = 0; nt < 3; ++nt) {
        int col = wn * 48 + nt * 16 + lm;
        bias[nt] = (col < 64) ? bq[h * 64 + col]
                 : (col < 128) ? bk[h * 64 + col - 64]
                 : bv[h * 64 + col - 128];
      }
#pragma unroll
      for (int mt = 0; mt < 3; ++mt) {
        int rowb = wm * 48 + mt * 16 + lg * 4;
        if (rowb < 80) {
#pragma unroll
          for (int r = 0; r < 4; ++r) {
            int rw = rowb + r;
#pragma unroll
            for (int nt = 0; nt < 3; ++nt) {
              int col = wn * 48 + nt * 16 + lm;
              float val = acc[mt][nt][r] + bias[nt];
              if (col < 128)
                *(bf16*)(sQK + rw * 256 + (((col >> 3) ^ (rw & 7)) << 4) + (col & 7) * 2) = (bf16)val;
              else
                vbuf[rw * 64 + (col - 128)] = (bf16)val;
            }
          }
        }
      }
    }
    __syncthreads();  // barrier B: qkv visible to all waves

    // ---- scores via MFMA (wave = local batch), softmax in-register ----
    {
      const int b = wave;
      f32x4 sv = {0.f, 0.f, 0.f, 0.f};
      const int rowa = b * 10 + lm;        // lm>=10: garbage rows, masked below
      const int x7r = rowa & 7;
#pragma unroll
      for (int kk = 0; kk < 2; ++kk) {
        bf16x8 qf = *(const bf16x8*)(sQK + rowa * 256 + (((kk * 4 + lg) ^ x7r) << 4));
        bf16x8 kf = *(const bf16x8*)(sQK + rowa * 256 + (((8 + kk * 4 + lg) ^ x7r) << 4));
        sv = __builtin_amdgcn_mfma_f32_16x16x32_bf16(qf, kf, sv, 0, 0, 0);
      }
      // C layout: row i = lg*4+r, col j = lm. softmax over j via 16-lane shuffles.
#pragma unroll
      for (int r = 0; r < 4; ++r) {
        float val = (lm < 10) ? sv[r] * 0.125f : -1e30f;   // mask pad cols
        float mx = val;
#pragma unroll
        for (int off = 1; off < 16; off <<= 1) mx = fmaxf(mx, __shfl_xor(mx, off));
        float e = __expf(val - mx);
        float ssum = e;
#pragma unroll
        for (int off = 1; off < 16; off <<= 1) ssum += __shfl_xor(ssum, off);
        int i = lg * 4 + r;
        if (i < 10 && lm < 12) scp[(b * 10 + i) * 12 + lm] = e / ssum;
      }
    }

    // ---- PV (lane <-> d), coalesced O store (wave-local, no barrier) ----
    {
      const int b = wave;
      const int d = lane;                  // 0..63
      float vv[10];
#pragma unroll
      for (int j = 0; j < 10; ++j) vv[j] = (float)vbuf[(b * 10 + j) * 64 + d];
      bf16* Ob = O + ((size_t)(b0 + b) * 10) * 512 + h * 64 + d;
#pragma unroll
      for (int i = 0; i < 10; ++i) {
        const float* ar = scp + (b * 10 + i) * 12;
        f32x4 a0 = *(const f32x4*)ar;
        f32x4 a1 = *(const f32x4*)(ar + 4);
        float o = a0[0] * vv[0] + a0[1] * vv[1] + a0[2] * vv[2] + a0[3] * vv[3]
                + a1[0] * vv[4] + a1[1] * vv[5] + a1[2] * vv[6] + a1[3] * vv[7]
                + ar[8] * vv[8] + ar[9] * vv[9];
        Ob[(size_t)i * 512] = (bf16)o;     // 64 lanes x 2B = 128B contiguous
      }
    }
    // no trailing barrier: next head's GEMM touches only sA + registers;
    // barrier A protects sQK/vbuf/scp before the next spill.
  }

  // ================= Phase 2: O @ Wo^T + bo -> LN -> sum over F =================
  // BK=32, dbuf A+B, raw barriers + counted vmcnt. Paired-row LDS layout:
  // granule g of row R at (R>>1)*128 + (R&1)*64 + ((g ^ ((R>>1)&3))<<4),
  // staged via linear 1024B copies with pre-swizzled global source.
  {
    char* Ab0 = smem;
    char* Ab1 = smem + 5120;
    char* Bb0 = smem + 10240;
    char* Bb1 = smem + 43008;
    float* partial = (float*)(smem + 83200);  // [80][4][2]
    float* stats   = (float*)(smem + 85760);  // [80][2]
    const char* Ob = (const char*)(O + (size_t)blockIdx.x * 80 * 512);
    const char* Wb = (const char*)wob;

    const int srow  = lane >> 2;                       // source row within 16-row copy
    const int sgran = (lane & 3) ^ ((lane >> 3) & 3);  // pre-swizzled source granule

    f32x4 acc[3][8];
#pragma unroll
    for (int i = 0; i < 3; ++i)
#pragma unroll
      for (int j = 0; j < 8; ++j) { f32x4 z = {0.f, 0.f, 0.f, 0.f}; acc[i][j] = z; }

    // stage slab s into (AbN, BbN): B 4 copies/wave, A 1 copy for waves 0-4
#define STAGE2(AbN, BbN, s_)                                                     \
    {                                                                            \
      size_t co = (size_t)(s_) * 64 + sgran * 16;                                \
      _Pragma("unroll")                                                          \
      for (int j = 0; j < 4; ++j) {                                              \
        int R0 = (wave * 4 + j) * 16;                                            \
        async_copy16((BbN) + R0 * 64, Wb + (size_t)(R0 + srow) * 1024 + co);     \
      }                                                                          \
      if (wave < 5) {                                                            \
        int R0 = wave * 16;                                                      \
        async_copy16((AbN) + R0 * 64, Ob + (size_t)(R0 + srow) * 1024 + co);     \
      }                                                                          \
    }

    STAGE2(Ab0, Bb0, 0);                   // prologue

    for (int s = 0; s < 16; ++s) {
      char* AbC = (s & 1) ? Ab1 : Ab0;
      char* BbC = (s & 1) ? Bb1 : Bb0;
      char* AbN = (s & 1) ? Ab0 : Ab1;
      char* BbN = (s & 1) ? Bb0 : Bb1;
      if (s != 15) {
        STAGE2(AbN, BbN, s + 1);
        if (wave < 5) asm volatile("s_waitcnt vmcnt(5)" ::: "memory");
        else          asm volatile("s_waitcnt vmcnt(4)" ::: "memory");
      } else {
        asm volatile("s_waitcnt vmcnt(0)" ::: "memory");
      }
      __builtin_amdgcn_sched_barrier(0);
      __builtin_amdgcn_s_barrier();        // slab s visible
      __builtin_amdgcn_sched_barrier(0);

      bf16x8 a2[3], b2[8];
#pragma unroll
      for (int mt = 0; mt < 3; ++mt)
        if (mt < 2 || wm == 0) {
          int m = wm * 48 + mt * 16 + lm;
          a2[mt] = *(const bf16x8*)(AbC + (m >> 1) * 128 + (m & 1) * 64 + (((lg ^ ((m >> 1) & 3))) << 4));
        }
#pragma unroll
      for (int nt = 0; nt < 8; ++nt) {
        int n = wn * 128 + nt * 16 + lm;
        b2[nt] = *(const bf16x8*)(BbC + (n >> 1) * 128 + (n & 1) * 64 + (((lg ^ ((n >> 1) & 3))) << 4));
      }
      __builtin_amdgcn_s_setprio(1);
#pragma unroll
      for (int mt = 0; mt < 3; ++mt)
        if (mt < 2 || wm == 0)
#pragma unroll
          for (int nt = 0; nt < 8; ++nt)
            acc[mt][nt] = __builtin_amdgcn_mfma_f32_16x16x32_bf16(a2[mt], b2[nt], acc[mt][nt], 0, 0, 0);
      __builtin_amdgcn_s_setprio(0);

      asm volatile("s_waitcnt lgkmcnt(0)" ::: "memory");
      __builtin_amdgcn_sched_barrier(0);
      __builtin_amdgcn_s_barrier();        // release slab s buffers
      __builtin_amdgcn_sched_barrier(0);
    }

    // + bias
#pragma unroll
    for (int nt = 0; nt < 8; ++nt) {
      float bb = bo[wn * 128 + nt * 16 + lm];
#pragma unroll
      for (int mt = 0; mt < 3; ++mt)
#pragma unroll
        for (int r = 0; r < 4; ++r) acc[mt][nt][r] += bb;
    }

    // per-row mean/var: lane-local over 8 nt, then xor-shuffle across 16-lane col group
#pragma unroll
    for (int mt = 0; mt < 3; ++mt)
#pragma unroll
      for (int r = 0; r < 4; ++r) {
        float s1 = 0.f, s2 = 0.f;
#pragma unroll
        for (int nt = 0; nt < 8; ++nt) { float v = acc[mt][nt][r]; s1 += v; s2 += v * v; }
#pragma unroll
        for (int off = 1; off < 16; off <<= 1) {
          s1 += __shfl_xor(s1, off);
          s2 += __shfl_xor(s2, off);
        }
        if (lm == 0) {
          int row = wm * 48 + mt * 16 + lg * 4 + r;
          if (row < 80) {
            partial[(row * 4 + wn) * 2]     = s1;
            partial[(row * 4 + wn) * 2 + 1] = s2;
          }
        }
      }
    __syncthreads();
    if (tid < 80) {
      float s1 = 0.f, s2 = 0.f;
#pragma unroll
      for (int w = 0; w < 4; ++w) {
        s1 += partial[(tid * 4 + w) * 2];
        s2 += partial[(tid * 4 + w) * 2 + 1];
      }
      float mu = s1 * (1.f / 512.f);
      float var = s2 * (1.f / 512.f) - mu * mu;
      stats[tid * 2]     = mu;
      stats[tid * 2 + 1] = rsqrtf(var + EPS);
    }
    __syncthreads();
    // normalized values -> LDS bf16 (GEMM buffers dead), stride 520
    bf16* lnb = (bf16*)smem;
#pragma unroll
    for (int mt = 0; mt < 3; ++mt)
#pragma unroll
      for (int r = 0; r < 4; ++r) {
        int row = wm * 48 + mt * 16 + lg * 4 + r;
        if (row < 80) {
          float mu = stats[row * 2], rr = stats[row * 2 + 1];
#pragma unroll
          for (int nt = 0; nt < 8; ++nt) {
            int col = wn * 128 + nt * 16 + lm;
            lnb[row * 520 + col] = (bf16)((acc[mt][nt][r] - mu) * rr);
          }
        }
      }
    __syncthreads();
    // out[b,n] = gamma[n]*sum_f lnv + 10*beta[n]
#pragma unroll
    for (int u = 0; u < 8; ++u) {
      int id = tid + u * 512;              // 4096 outputs: 8b x 512n
      int b = id >> 9, n = id & 511;
      float ssum = 0.f;
#pragma unroll
      for (int f = 0; f < 10; ++f) ssum += (float)lnb[(b * 10 + f) * 520 + n];
      out[((size_t)blockIdx.x * 8 + b) * 512 + n] = gamma[n] * ssum + 10.f * beta[n];
    }
  }
#undef STAGE2
}

extern "C" void kernel_launch(void* const* d_in, const int* in_sizes, int n_in,
                              void* d_out, int out_size, void* d_ws, size_t ws_size,
                              hipStream_t stream) {
  const float* x     = (const float*)d_in[0];
  const float* Wf    = (const float*)d_in[1];
  const float* bfv   = (const float*)d_in[2];
  const float* Wq    = (const float*)d_in[3];
  const float* Wk    = (const float*)d_in[4];
  const float* Wv    = (const float*)d_in[5];
  const float* bq    = (const float*)d_in[6];
  const float* bk    = (const float*)d_in[7];
  const float* bv    = (const float*)d_in[8];
  const float* Wo    = (const float*)d_in[9];
  const float* bo    = (const float*)d_in[10];
  const float* gamma = (const float*)d_in[11];
  const float* beta  = (const float*)d_in[12];
  float* out = (float*)d_out;

  char* ws = (char*)d_ws;
  bf16* O    = (bf16*)ws;                              // 167,772,160 B
  bf16* wqkv = (bf16*)(ws + O_BYTES);                  // 1,572,864 B
  bf16* wob  = (bf16*)(ws + O_BYTES + WQKV_BYTES);     // 524,288 B

  pack_weights<<<1024, 256, 0, stream>>>(Wq, Wk, Wv, Wo, wqkv, wob);
  kern_fused<<<2048, 512, 0, stream>>>(x, Wf, bfv, wqkv, bq, bk, bv, O,
                                       wob, bo, gamma, beta, out);
}